// Round 1
// baseline (118.222 us; speedup 1.0000x reference)
//
#include <hip/hip_runtime.h>
#include <math.h>

#define NROWS  2048
#define VOCAB  50000
#define SRC_L  400
#define PAD_ID 1

// Kernel A: one block per row.
//  - streams the row of p_gen, tracks max of (1-sw)*p_gen with first-index tie-break
//  - stages src/p_copy row in LDS, builds full scores at copied positions
//    (duplicate src indices summed in occurrence order, matching np.add.at)
//  - computes target score and per-row loss contribution -> row_loss[row]
//  - writes pred as float to out[1+row]
__global__ __launch_bounds__(256) void pg_row_kernel(
    const float* __restrict__ p_gen,
    const float* __restrict__ p_copy,
    const float* __restrict__ p_switch,
    const int*   __restrict__ tgt,
    const int*   __restrict__ src,
    float* __restrict__ out,        // [0]=loss (kernel B), [1..NROWS]=pred
    float* __restrict__ row_loss)   // ws, NROWS floats
{
    const int row = blockIdx.x;
    const int tid = threadIdx.x;

    const float sw  = p_switch[row];
    const float osw = 1.0f - sw;
    const float* __restrict__ g = p_gen + (size_t)row * VOCAB;

    __shared__ int   s_src[SRC_L];
    __shared__ float s_pc [SRC_L];
    for (int j = tid; j < SRC_L; j += 256) {
        s_src[j] = src[(size_t)row * SRC_L + j];
        s_pc [j] = p_copy[(size_t)row * SRC_L + j];
    }
    __syncthreads();

    float bestv = -1.0f;            // all scores are >= 0
    int   besti = 0x7fffffff;

    // ---- streaming gen-score scan (float4 vectorized; 50000 % 4 == 0) ----
    const float4* __restrict__ g4 = (const float4*)g;
    for (int t = tid; t < VOCAB / 4; t += 256) {
        float4 v = g4[t];
        const int b = t << 2;
        float a;
        a = __fmul_rn(v.x, osw);
        if (a > bestv || (a == bestv && b     < besti)) { bestv = a; besti = b;     }
        a = __fmul_rn(v.y, osw);
        if (a > bestv || (a == bestv && b + 1 < besti)) { bestv = a; besti = b + 1; }
        a = __fmul_rn(v.z, osw);
        if (a > bestv || (a == bestv && b + 2 < besti)) { bestv = a; besti = b + 2; }
        a = __fmul_rn(v.w, osw);
        if (a > bestv || (a == bestv && b + 3 < besti)) { bestv = a; besti = b + 3; }
    }

    // ---- copied-position candidates (full scores) ----
    for (int j = tid; j < SRC_L; j += 256) {
        const int v = s_src[j];
        float sum = 0.0f;
        for (int k = 0; k < SRC_L; ++k)          // occurrence-order accumulation
            if (s_src[k] == v) sum = __fadd_rn(sum, s_pc[k]);
        const float cand = __fadd_rn(__fmul_rn(sw, sum), __fmul_rn(osw, g[v]));
        if (cand > bestv || (cand == bestv && v < besti)) { bestv = cand; besti = v; }
    }

    // ---- target score partial sum ----
    const int tv = tgt[row];
    float tsum = 0.0f;
    for (int k = tid; k < SRC_L; k += 256)
        if (s_src[k] == tv) tsum += s_pc[k];

    // ---- wave (64-lane) reduction ----
    for (int off = 32; off > 0; off >>= 1) {
        const float ov = __shfl_down(bestv, off);
        const int   oi = __shfl_down(besti, off);
        if (ov > bestv || (ov == bestv && oi < besti)) { bestv = ov; besti = oi; }
        tsum += __shfl_down(tsum, off);
    }

    __shared__ float wv[4];
    __shared__ int   wi[4];
    __shared__ float wsum[4];
    const int wave = tid >> 6;
    if ((tid & 63) == 0) { wv[wave] = bestv; wi[wave] = besti; wsum[wave] = tsum; }
    __syncthreads();

    if (tid == 0) {
        for (int w = 1; w < 4; ++w) {
            if (wv[w] > bestv || (wv[w] == bestv && wi[w] < besti)) {
                bestv = wv[w]; besti = wi[w];
            }
            tsum += wsum[w];
        }
        out[1 + row] = (float)besti;

        const float ts = __fadd_rn(__fmul_rn(sw, tsum), __fmul_rn(osw, g[tv]));
        row_loss[row] = (tv != PAD_ID) ? logf(ts + 1e-12f) : 0.0f;
    }
}

// Kernel B: reduce row losses -> out[0] = -sum/N
__global__ __launch_bounds__(256) void pg_loss_kernel(
    const float* __restrict__ row_loss,
    float* __restrict__ out)
{
    float s = 0.0f;
    for (int i = threadIdx.x; i < NROWS; i += 256) s += row_loss[i];
    for (int off = 32; off > 0; off >>= 1) s += __shfl_down(s, off);

    __shared__ float wsum[4];
    if ((threadIdx.x & 63) == 0) wsum[threadIdx.x >> 6] = s;
    __syncthreads();
    if (threadIdx.x == 0) {
        const float t = wsum[0] + wsum[1] + wsum[2] + wsum[3];
        out[0] = -t / (float)NROWS;
    }
}

extern "C" void kernel_launch(void* const* d_in, const int* in_sizes, int n_in,
                              void* d_out, int out_size, void* d_ws, size_t ws_size,
                              hipStream_t stream) {
    const float* p_gen    = (const float*)d_in[0];
    const float* p_copy   = (const float*)d_in[1];
    const float* p_switch = (const float*)d_in[2];
    const int*   tgt      = (const int*)d_in[3];
    const int*   src      = (const int*)d_in[4];

    float* out      = (float*)d_out;
    float* row_loss = (float*)d_ws;

    pg_row_kernel<<<NROWS, 256, 0, stream>>>(p_gen, p_copy, p_switch, tgt, src,
                                             out, row_loss);
    pg_loss_kernel<<<1, 256, 0, stream>>>(row_loss, out);
}

// Round 2
// 85.815 us; speedup vs baseline: 1.3776x; 1.3776x over previous
//
#include <hip/hip_runtime.h>
#include <math.h>

#define NROWS  2048
#define VOCAB  50000
#define SRC_L  400
#define PAD_ID 1
#define NBM    1568   // ceil(50000/32)=1563 dwords, padded
#define HSZ    1024   // hash slots (load factor ~0.4)
#define QCAP   64     // duplicate queue capacity

// Kernel A: one block per row.
// Phase 0: stage src/p_copy rows in LDS; clear bitmap/hash.
// Phase 1: build presence bitmap + hash(v -> scatter-add sum). Unique values
//          get sum=p_copy[j] (exact: 0+p). Duplicate values enqueued.
// Phase 2: wave 0 resolves duplicates with a lane-parallel, ascending-k fold
//          (bit-exact vs np.add.at occurrence order).
// Phase 3: stream p_gen row as float4; gen candidate = (1-sw)*g (exact, fmul_rn);
//          bitmap hit -> copy candidate = sw*S_v + (1-sw)*g (exact) using the
//          STREAMED g value (no gather). g[tgt] captured from the stream too.
//          Updates strictly in ascending vocab index -> first-index tie-break.
// Phase 4: wave/block argmax + target-sum reduction; row loss to ws.
__global__ __launch_bounds__(256) void pg_row_kernel(
    const float* __restrict__ p_gen,
    const float* __restrict__ p_copy,
    const float* __restrict__ p_switch,
    const int*   __restrict__ tgt,
    const int*   __restrict__ src,
    float* __restrict__ out,        // [0]=loss (kernel B), [1..NROWS]=pred
    float* __restrict__ row_loss)   // ws, NROWS floats
{
    const int row = blockIdx.x;
    const int tid = threadIdx.x;

    const float sw  = p_switch[row];
    const float osw = 1.0f - sw;
    const float* __restrict__ g = p_gen + (size_t)row * VOCAB;
    const int tv = tgt[row];

    __shared__ int      s_src[SRC_L];
    __shared__ float    s_pc [SRC_L];
    __shared__ unsigned s_bm [NBM];
    __shared__ int      s_key[HSZ];
    __shared__ float    s_val[HSZ];
    __shared__ int      s_qs [QCAP];
    __shared__ int      s_qv [QCAP];
    __shared__ int      s_qn;
    __shared__ float    s_gtv;

    // ---- phase 0: stage + clear ----
    for (int j = tid; j < SRC_L; j += 256) {
        s_src[j] = src[(size_t)row * SRC_L + j];
        s_pc [j] = p_copy[(size_t)row * SRC_L + j];
    }
    for (int i = tid; i < NBM; i += 256) s_bm[i] = 0u;
    for (int i = tid; i < HSZ; i += 256) s_key[i] = -1;
    if (tid == 0) s_qn = 0;
    __syncthreads();

    // ---- phase 1: bitmap + hash insert ----
    for (int j = tid; j < SRC_L; j += 256) {
        const int   v = s_src[j];
        const float p = s_pc [j];
        atomicOr(&s_bm[v >> 5], 1u << (v & 31));
        unsigned s = (((unsigned)v) * 2654435761u) >> 22;   // 10 bits
        while (true) {
            const int old = atomicCAS(&s_key[s], -1, v);
            if (old == -1) { s_val[s] = p; break; }          // owner (unique so far)
            if (old == v) {                                  // duplicate value
                const int qi = atomicAdd(&s_qn, 1);
                if (qi < QCAP) { s_qs[qi] = (int)s; s_qv[qi] = v; }
                break;
            }
            s = (s + 1) & (HSZ - 1);
        }
    }
    __syncthreads();

    // ---- phase 2: wave 0 resolves duplicates (ascending-k exact fold) ----
    if (tid < 64) {
        int qn = s_qn; if (qn > QCAP) qn = QCAP;
        const int lane = tid;
        for (int q = 0; q < qn; ++q) {
            const int slot = s_qs[q];
            const int v    = s_qv[q];
            float S = 0.0f;
            #pragma unroll
            for (int r = 0; r < 7; ++r) {
                const int k  = (r << 6) + lane;
                const int kk = (k < SRC_L) ? k : 0;
                const bool m = (k < SRC_L) && (s_src[kk] == v);
                const float pk = s_pc[kk];
                unsigned long long mask = __ballot(m);
                while (mask) {
                    const int l = __ffsll((long long)mask) - 1;
                    S = __fadd_rn(S, __shfl(pk, l));
                    mask &= mask - 1;
                }
            }
            if (lane == 0) s_val[slot] = S;
        }
    }
    __syncthreads();

    float bestv = -1.0f;            // all scores >= 0
    int   besti = 0x7fffffff;

    // ---- phase 3: stream p_gen (float4), inline copy candidates ----
    const float4* __restrict__ g4 = (const float4*)g;
    for (int t = tid; t < VOCAB / 4; t += 256) {
        const float4 vv = g4[t];
        const int b = t << 2;
        const unsigned m4 = (s_bm[b >> 5] >> (b & 31)) & 0xFu;

        #define PG_ELT(i, comp)                                                 \
        {                                                                       \
            const float a = __fmul_rn(comp, osw);                               \
            if (a > bestv) { bestv = a; besti = b + (i); }                      \
            if (m4 & (1u << (i))) {                                             \
                const int v = b + (i);                                          \
                unsigned s = (((unsigned)v) * 2654435761u) >> 22;               \
                while (s_key[s] != v) s = (s + 1) & (HSZ - 1);                  \
                const float cand = __fadd_rn(__fmul_rn(sw, s_val[s]),           \
                                             __fmul_rn(osw, comp));             \
                if (cand > bestv) { bestv = cand; besti = v; }                  \
            }                                                                   \
        }
        PG_ELT(0, vv.x)
        PG_ELT(1, vv.y)
        PG_ELT(2, vv.z)
        PG_ELT(3, vv.w)
        #undef PG_ELT

        if (tv >= b && tv < b + 4) {        // capture g[tgt] from the stream
            float gt = vv.x;
            if      (tv == b + 1) gt = vv.y;
            else if (tv == b + 2) gt = vv.z;
            else if (tv == b + 3) gt = vv.w;
            s_gtv = gt;
        }
    }

    // ---- target copy-sum partials (cheap: 2 LDS iters/thread) ----
    float tsum = 0.0f;
    for (int k = tid; k < SRC_L; k += 256)
        if (s_src[k] == tv) tsum += s_pc[k];

    // ---- wave (64-lane) reduction ----
    for (int off = 32; off > 0; off >>= 1) {
        const float ov = __shfl_down(bestv, off);
        const int   oi = __shfl_down(besti, off);
        if (ov > bestv || (ov == bestv && oi < besti)) { bestv = ov; besti = oi; }
        tsum += __shfl_down(tsum, off);
    }

    __shared__ float wv[4];
    __shared__ int   wi[4];
    __shared__ float wsum[4];
    const int wave = tid >> 6;
    if ((tid & 63) == 0) { wv[wave] = bestv; wi[wave] = besti; wsum[wave] = tsum; }
    __syncthreads();

    if (tid == 0) {
        for (int w = 1; w < 4; ++w) {
            if (wv[w] > bestv || (wv[w] == bestv && wi[w] < besti)) {
                bestv = wv[w]; besti = wi[w];
            }
            tsum += wsum[w];
        }
        out[1 + row] = (float)besti;

        const float ts = __fadd_rn(__fmul_rn(sw, tsum), __fmul_rn(osw, s_gtv));
        row_loss[row] = (tv != PAD_ID) ? logf(ts + 1e-12f) : 0.0f;
    }
}

// Kernel B: reduce row losses -> out[0] = -sum/N
__global__ __launch_bounds__(256) void pg_loss_kernel(
    const float* __restrict__ row_loss,
    float* __restrict__ out)
{
    float s = 0.0f;
    for (int i = threadIdx.x; i < NROWS; i += 256) s += row_loss[i];
    for (int off = 32; off > 0; off >>= 1) s += __shfl_down(s, off);

    __shared__ float wsum[4];
    if ((threadIdx.x & 63) == 0) wsum[threadIdx.x >> 6] = s;
    __syncthreads();
    if (threadIdx.x == 0) {
        const float t = wsum[0] + wsum[1] + wsum[2] + wsum[3];
        out[0] = -t / (float)NROWS;
    }
}

extern "C" void kernel_launch(void* const* d_in, const int* in_sizes, int n_in,
                              void* d_out, int out_size, void* d_ws, size_t ws_size,
                              hipStream_t stream) {
    const float* p_gen    = (const float*)d_in[0];
    const float* p_copy   = (const float*)d_in[1];
    const float* p_switch = (const float*)d_in[2];
    const int*   tgt      = (const int*)d_in[3];
    const int*   src      = (const int*)d_in[4];

    float* out      = (float*)d_out;
    float* row_loss = (float*)d_ws;

    pg_row_kernel<<<NROWS, 256, 0, stream>>>(p_gen, p_copy, p_switch, tgt, src,
                                             out, row_loss);
    pg_loss_kernel<<<1, 256, 0, stream>>>(row_loss, out);
}